// Round 12
// baseline (3993824.609 us; speedup 1.0000x reference)
//
#include <hip/hip_runtime.h>

#define B_ 1024
#define S_ 64
#define D_ 300
#define DP_ 320
#define H_ 512
#define G3_ 1536
#define Z_ 128
#define NCH1 5    // phase-1 chunks per K-half (K=320 -> 2 x 160)
#define NCH2 8    // phase-2 chunks per K-half (K=512 -> 2 x 256)
#define CSTR 64   // counter stride in dwords (256 B line per chain)

typedef __bf16 bf16x8 __attribute__((ext_vector_type(8)));
typedef float f32x4 __attribute__((ext_vector_type(4)));

// cached global->LDS DMA (aux=0) — head_gemm only
#define GLLD(g, l) __builtin_amdgcn_global_load_lds( \
    (const __attribute__((address_space(1))) void*)(g), \
    (__attribute__((address_space(3))) void*)(l), 16, 0, 0)

#define MFMA(a, b, c) __builtin_amdgcn_mfma_f32_16x16x32_bf16((a), (b), (c), 0, 0, 0)

// ---------------- prep kernels ----------------
// text is [b][s][d]; Xbf re-laid-out to [s][b][dp]; 8 rows per block
__global__ __launch_bounds__(320) void prep_text(const float* __restrict__ text,
                                                 __bf16* __restrict__ Xbf) {
    int dp = threadIdx.x;         // 320
    int base = blockIdx.x * 8;    // 8192 blocks
#pragma unroll
    for (int r = 0; r < 8; ++r) {
        int bs = base + r;        // bs = b*S + s
        int b = bs >> 6, s = bs & 63;
        float v = (dp < D_) ? text[(size_t)bs * D_ + dp] : 0.f;
        Xbf[((size_t)s * B_ + b) * DP_ + dp] = (__bf16)v;
    }
}

__global__ __launch_bounds__(256) void prep_w(
    const float* __restrict__ Wih_f, const float* __restrict__ Whh_f,
    const float* __restrict__ Wih_b, const float* __restrict__ Whh_b,
    const float* __restrict__ W_mu, const float* __restrict__ W_sig,
    __bf16* __restrict__ Wk1, __bf16* __restrict__ Wk2, __bf16* __restrict__ Wcat,
    unsigned* __restrict__ cnt) {
    const int n1 = 2 * G3_ * DP_;       // 983040
    const int n2 = 2 * G3_ * H_;        // 1572864
    int i = blockIdx.x * 256 + threadIdx.x;
    if (i < 2048) cnt[i] = 0u;          // fold counter zeroing in here
    if (i < n1) {
        int dir = i / (G3_ * DP_);
        int rem = i - dir * (G3_ * DP_);
        int r = rem / DP_;
        int k = rem - r * DP_;
        const float* W = dir ? Wih_b : Wih_f;
        Wk1[i] = (k < D_) ? (__bf16)W[(size_t)r * D_ + k] : (__bf16)0.f;
    } else if (i < n1 + n2) {
        int jj = i - n1;
        int dir = jj / (G3_ * H_);
        int rem = jj - dir * (G3_ * H_);
        int r = rem / H_;
        int k = rem - r * H_;
        const float* W = dir ? Whh_b : Whh_f;
        Wk2[jj] = (__bf16)W[(size_t)r * H_ + k];
    } else {
        int idx = i - n1 - n2;          // < 131072
        int z = idx >> 9, k = idx & 511;
        Wcat[idx] = (__bf16)(z < 128 ? W_mu[(size_t)z * H_ + k]
                                     : W_sig[(size_t)(z - 128) * H_ + k]);
    }
}

// ---------------- persistent bidirectional GRU ----------------
// r12: 256 blocks x 512 threads (8 waves, 2 waves/SIMD, 1 block/CU — 256
// blocks on 256 CUs always co-reside). Block = 64 batch rows x 32 h-cols,
// hosting TWO chains: waves 0-3 = forward dir, waves 4-7 = backward dir of
// the SAME rows. Wave i lands on SIMD i&3 => every SIMD holds one fwd + one
// bwd wave; when one chain stalls on its poll, the partner chain computes.
// Wave role: dir = w>>2, jt = w&1 (16-col tile), kh = (w>>1)&1 (K-half).
// Whh K-half fragments register-resident (96 regs; fits the 256-reg/wave cap
// 2 waves/SIMD imposes — r9's spill lesson). Wih streamed. Cross-K-half
// reduction through a 32 KB bf16 LDS buffer with per-wave-pair LDS flags —
// NO __syncthreads in the step loop (chains stay decoupled). Chain = 16
// same-XCD blocks (bid&7, r8-proven); global sync = r11's exact proven
// poll/inc form, 64 incs per chain-step. h publish = plain packed stores;
// h read = plain loads after buffer_inv (r11-proven). s=0 skips exchange.
__global__ __launch_bounds__(512) void gru_persist(
    const __bf16* __restrict__ Xbf, const __bf16* __restrict__ Wk1,
    const __bf16* __restrict__ Wk2,
    const float* __restrict__ bih_f, const float* __restrict__ bhh_f,
    const float* __restrict__ bih_b, const float* __restrict__ bhh_b,
    const int* __restrict__ lens,
    __bf16* __restrict__ Hb0, __bf16* __restrict__ Hb1,
    float* __restrict__ Ssum, unsigned* __restrict__ cnt)
{
    __shared__ __align__(16) unsigned short pbuf[8][32 * 64];  // 32 KB partials
    __shared__ unsigned dflag[8];   // dump counters (per wave)
    __shared__ unsigned cflag[8];   // consumed counters (per wave's region)

    const int bid = blockIdx.x;
    const int xcd = bid & 7;
    const int w   = bid >> 3;              // 0..31 within XCD
    const int rowg = xcd * 2 + (w >> 4);   // 0..15
    const int colb = w & 15;               // 0..15
    const int b0 = rowg * 64;

    const int tid = threadIdx.x;
    const int wave = tid >> 6;             // 0..7
    const int lane = tid & 63;
    const int dir = wave >> 2;
    const int jt  = wave & 1;
    const int kh  = (wave >> 1) & 1;
    const int partner = wave ^ 2;          // kh flipped

    const int chain = dir * 16 + rowg;     // 0..31 (16 blocks, same XCD)
    unsigned* const gcnt = cnt + chain * CSTR;

    const int jcol = colb * 32 + jt * 16 + (lane & 15);    // 0..511
    const int kq8  = (lane >> 4) * 8;

    if (tid < 8) { dflag[tid] = 0u; cflag[tid] = 0u; }
    __syncthreads();   // once, before the loop

    __bf16* HB[2] = { Hb0, Hb1 };
    // h A-frag base: row b0+(lane&15), K col kq8 + kh*256
    const size_t hbase = (size_t)(dir * B_ + b0 + (lane & 15)) * H_ + kq8 + kh * (NCH2 * 32);
    // X A-frag base: row b0+(lane&15), K col kq8 + kh*160
    const __bf16* xlane = Xbf + (size_t)(b0 + (lane & 15)) * DP_ + kq8 + kh * (NCH1 * 32);

    // Wih stream pointers (this wave's K-half)
    const __bf16* w1p[3];
#pragma unroll
    for (int g = 0; g < 3; ++g)
        w1p[g] = Wk1 + ((size_t)dir * G3_ + g * H_ + jcol) * DP_ + kq8 + kh * (NCH1 * 32);

    // Whh K-half fragments register-resident: 8 chunks x 3 gates x 4 regs = 96
    bf16x8 w2c[NCH2][3];
    {
        const __bf16* w2p[3];
#pragma unroll
        for (int g = 0; g < 3; ++g)
            w2p[g] = Wk2 + ((size_t)dir * G3_ + g * H_ + jcol) * H_ + kq8 + kh * (NCH2 * 32);
#pragma unroll
        for (int c = 0; c < NCH2; ++c)
#pragma unroll
            for (int g = 0; g < 3; ++g)
                w2c[c][g] = *(const bf16x8*)(w2p[g] + c * 32);
    }

    const float* bih = dir ? bih_b : bih_f;
    const float* bhh = dir ? bhh_b : bhh_f;
    const float b_r  = bih[jcol] + bhh[jcol];
    const float b_z  = bih[H_ + jcol] + bhh[H_ + jcol];
    const float b_ni = bih[2 * H_ + jcol];
    const float b_nh = bhh[2 * H_ + jcol];

    // this wave's epilogue rows: mt-group kh*2+mtl
    unsigned lenp[2];
#pragma unroll
    for (int mtl = 0; mtl < 2; ++mtl) {
        int r0 = b0 + (kh * 2 + mtl) * 16 + (lane >> 4) * 4;
        lenp[mtl] = (unsigned)(lens[r0] & 255) | ((unsigned)(lens[r0 + 1] & 255) << 8)
                  | ((unsigned)(lens[r0 + 2] & 255) << 16) | ((unsigned)(lens[r0 + 3] & 255) << 24);
    }

    float hreg[8], ssum[8];
#pragma unroll
    for (int i = 0; i < 8; ++i) { hreg[i] = 0.f; ssum[i] = 0.f; }

    for (int s = 0; s < S_; ++s) {
        const int sx = dir ? (S_ - 1 - s) : s;
        const __bf16* xs = xlane + (size_t)sx * (B_ * DP_);

        f32x4 acc[4][4];
#pragma unroll
        for (int mt = 0; mt < 4; ++mt)
#pragma unroll
            for (int p = 0; p < 4; ++p)
                acc[mt][p] = (f32x4){0.f, 0.f, 0.f, 0.f};

        // ---- phase 1 (K-half): x @ Wih^T, Wih streamed ----
#pragma unroll
        for (int c = 0; c < NCH1; ++c) {
            bf16x8 wf0 = *(const bf16x8*)(w1p[0] + c * 32);
            bf16x8 wf1 = *(const bf16x8*)(w1p[1] + c * 32);
            bf16x8 wf2 = *(const bf16x8*)(w1p[2] + c * 32);
            bf16x8 af[4];
#pragma unroll
            for (int mt = 0; mt < 4; ++mt)
                af[mt] = *(const bf16x8*)(xs + mt * (16 * DP_) + c * 32);
#pragma unroll
            for (int mt = 0; mt < 4; ++mt) {
                acc[mt][0] = MFMA(af[mt], wf0, acc[mt][0]);
                acc[mt][1] = MFMA(af[mt], wf1, acc[mt][1]);
                acc[mt][2] = MFMA(af[mt], wf2, acc[mt][2]);
            }
        }

        if (s > 0) {
            // ---- chain poll (r11-proven form): all 64 member waves @ s-1 ----
            if (lane == 0) {
                const unsigned tgt = 64u * (unsigned)s;
                unsigned it = 0;
                while (__hip_atomic_fetch_add(gcnt, 0u, __ATOMIC_RELAXED,
                                              __HIP_MEMORY_SCOPE_WORKGROUP) < tgt) {
                    if (++it > (1u << 20)) break;   // forward-progress escape
                }
            }
            asm volatile("buffer_inv" ::: "memory");

            // ---- phase 2 (K-half): h @ Whh^T, h via plain L2-hit loads ----
            const __bf16* hl = HB[s & 1] + hbase;
#pragma unroll
            for (int c = 0; c < NCH2; ++c) {
                bf16x8 af[4];
#pragma unroll
                for (int mt = 0; mt < 4; ++mt)
                    af[mt] = *(const bf16x8*)(hl + (size_t)(mt * 16) * H_ + c * 32);
#pragma unroll
                for (int mt = 0; mt < 4; ++mt) {
                    acc[mt][0] = MFMA(af[mt], w2c[c][0], acc[mt][0]);
                    acc[mt][1] = MFMA(af[mt], w2c[c][1], acc[mt][1]);
                    acc[mt][3] = MFMA(af[mt], w2c[c][2], acc[mt][3]);
                }
            }

            // wait until partner consumed my previous dump (region reuse)
            if (lane == 0) {
                unsigned it = 0;
                while (__hip_atomic_load(&cflag[wave], __ATOMIC_ACQUIRE,
                                         __HIP_MEMORY_SCOPE_WORKGROUP) < (unsigned)s) {
                    if (++it > (1u << 20)) break;
                }
            }
        }
        // s == 0: h = 0 -> gh = bhh exactly (folded into b_r/b_z/b_nh).

        // ---- dump the PARTNER's mt-half partials (bf16) into my region ----
        {
            unsigned short* dst = &pbuf[wave][0];
#pragma unroll
            for (int mtl = 0; mtl < 2; ++mtl) {
                const int mtp = (1 - kh) * 2 + mtl;
#pragma unroll
                for (int p = 0; p < 4; ++p)
#pragma unroll
                    for (int r = 0; r < 4; ++r) {
                        __bf16 v = (__bf16)acc[mtp][p][r];
                        dst[((mtl * 4 + p) * 4 + r) * 64 + lane] =
                            __builtin_bit_cast(unsigned short, v);
                    }
            }
        }
        if (lane == 0)
            __hip_atomic_fetch_add(&dflag[wave], 1u, __ATOMIC_RELEASE,
                                   __HIP_MEMORY_SCOPE_WORKGROUP);
        // ---- wait partner's dump, then reduce + cell + publish my rows ----
        if (lane == 0) {
            unsigned it = 0;
            while (__hip_atomic_load(&dflag[partner], __ATOMIC_ACQUIRE,
                                     __HIP_MEMORY_SCOPE_WORKGROUP) < (unsigned)(s + 1)) {
                if (++it > (1u << 20)) break;
            }
        }
        {
            const unsigned short* src = &pbuf[partner][0];
            __bf16* hb_w = HB[(s & 1) ^ 1];
            const bool store_lane = (lane & 1) == 0;
#pragma unroll
            for (int mtl = 0; mtl < 2; ++mtl) {
                const int mtg = kh * 2 + mtl;
#pragma unroll
                for (int reg = 0; reg < 4; ++reg) {
                    float pr[4];
#pragma unroll
                    for (int p = 0; p < 4; ++p) {
                        unsigned u = src[((mtl * 4 + p) * 4 + reg) * 64 + lane];
                        pr[p] = __builtin_bit_cast(float, u << 16);
                    }
                    const int i = mtl * 4 + reg;
                    const float g_r = acc[mtg][0][reg] + pr[0] + b_r;
                    const float g_z = acc[mtg][1][reg] + pr[1] + b_z;
                    const float g_i = acc[mtg][2][reg] + pr[2] + b_ni;
                    const float g_h = acc[mtg][3][reg] + pr[3] + b_nh;
                    const float r = 1.f / (1.f + __expf(-g_r));
                    const float z = 1.f / (1.f + __expf(-g_z));
                    const float n = 2.f / (1.f + __expf(-2.f * (g_i + r * g_h))) - 1.f;
                    const float hnew = (1.f - z) * n + z * hreg[i];
                    hreg[i] = hnew;
                    if (((lenp[mtl] >> (reg * 8)) & 255u) > (unsigned)s) ssum[i] += hnew;
                    __bf16 hb16 = (__bf16)hnew;
                    unsigned short myb = __builtin_bit_cast(unsigned short, hb16);
                    unsigned ob = (unsigned)__shfl_xor((int)(unsigned)myb, 1, 64);
                    if (store_lane) {
                        const int b = b0 + mtg * 16 + (lane >> 4) * 4 + reg;
                        // plain cached store: write-through L1 -> same-XCD L2
                        *(unsigned*)(hb_w + (size_t)(dir * B_ + b) * H_ + jcol) =
                            (unsigned)myb | (ob << 16);
                    }
                }
            }
        }
        if (lane == 0)
            __hip_atomic_fetch_add(&cflag[partner], 1u, __ATOMIC_RELEASE,
                                   __HIP_MEMORY_SCOPE_WORKGROUP);
        // drain h stores to L2 before making the increment visible
        __builtin_amdgcn_s_waitcnt(0xF70);   // vmcnt(0)
        if (lane == 0 && s < S_ - 1)
            __hip_atomic_fetch_add(gcnt, 1u, __ATOMIC_RELAXED,
                                   __HIP_MEMORY_SCOPE_WORKGROUP);
    }

    // write masked sums (each wave owns its 2 mt x 4 reg values)
#pragma unroll
    for (int mtl = 0; mtl < 2; ++mtl)
#pragma unroll
        for (int reg = 0; reg < 4; ++reg) {
            const int b = b0 + (kh * 2 + mtl) * 16 + (lane >> 4) * 4 + reg;
            Ssum[(size_t)(dir * B_ + b) * H_ + jcol] = ssum[mtl * 4 + reg];
        }
}

// ---------------- head ----------------
__global__ __launch_bounds__(128) void avg_prep(const float* __restrict__ Ssum,
                                                const int* __restrict__ lens,
                                                __bf16* __restrict__ Avg) {
    int b = blockIdx.x, t = threadIdx.x;
    float inv = 0.5f / (float)lens[b];
    float4 a = *(const float4*)(Ssum + (size_t)b * H_ + t * 4);
    float4 c = *(const float4*)(Ssum + (size_t)(B_ + b) * H_ + t * 4);
    __bf16* dst = Avg + (size_t)b * H_ + t * 4;
    dst[0] = (__bf16)((a.x + c.x) * inv);
    dst[1] = (__bf16)((a.y + c.y) * inv);
    dst[2] = (__bf16)((a.z + c.z) * inv);
    dst[3] = (__bf16)((a.w + c.w) * inv);
}

// Avg[1024x512] @ Wcat[256x512]^T -> mu/sigma planes of out
__global__ __launch_bounds__(256) void head_gemm(
    const __bf16* __restrict__ Avg, const __bf16* __restrict__ Wcat,
    const float* __restrict__ b_mu, const float* __restrict__ b_sig,
    float* __restrict__ out)
{
    __shared__ __align__(16) __bf16 abuf[16 * 2048];   // 64 KB static
    const int bid = blockIdx.x;                        // 64
    const int mb = bid >> 2, jb = bid & 3;
    const int tid = threadIdx.x, wave = tid >> 6, lane = tid & 63;
    const int srow = tid >> 2, scol = (tid & 3) * 8;
    const __bf16* asrc = Avg + (size_t)(mb * 64 + srow) * H_ + scol;
    {
        __bf16* dst = abuf + wave * 512;
#pragma unroll
        for (int c = 0; c < 16; ++c) GLLD(asrc + c * 32, dst + c * 2048);
    }
    __syncthreads();
    const int j = jb * 64 + wave * 16 + (lane & 15);   // 0..255
    const int kq8 = (lane >> 4) * 8;
    const __bf16* wp = Wcat + (size_t)j * H_ + kq8;
    const int aoff = (lane & 15) * 32 + kq8;
    f32x4 acc[4];
#pragma unroll
    for (int mt = 0; mt < 4; ++mt) acc[mt] = (f32x4){0.f, 0.f, 0.f, 0.f};
#pragma unroll
    for (int c = 0; c < 16; ++c) {
        bf16x8 wf = *(const bf16x8*)(wp + c * 32);
#pragma unroll
        for (int mt = 0; mt < 4; ++mt) {
            bf16x8 af = *(const bf16x8*)(abuf + c * 2048 + aoff + mt * 512);
            acc[mt] = MFMA(af, wf, acc[mt]);
        }
    }
    const int gate = j >> 7, z = j & 127;
    const float bias = gate ? b_sig[z] : b_mu[z];
#pragma unroll
    for (int mt = 0; mt < 4; ++mt)
#pragma unroll
        for (int reg = 0; reg < 4; ++reg) {
            const int b = mb * 64 + mt * 16 + (lane >> 4) * 4 + reg;
            float v = acc[mt][reg] + bias;
            v = v >= 0.f ? v : 0.2f * v;
            if (gate) v = __expf(v);
            out[(size_t)(1 + gate) * B_ * Z_ + (size_t)b * Z_ + z] = v;
        }
}

__global__ __launch_bounds__(256) void final_k(const float* __restrict__ eps,
                                               float* __restrict__ out) {
    int i = blockIdx.x * 256 + threadIdx.x;    // 131072
    out[i] = eps[i] * out[2 * B_ * Z_ + i] + out[B_ * Z_ + i];
}

extern "C" void kernel_launch(void* const* d_in, const int* in_sizes, int n_in,
                              void* d_out, int out_size, void* d_ws, size_t ws_size,
                              hipStream_t stream) {
    const float* text  = (const float*)d_in[0];
    const int*   lens  = (const int*)  d_in[1];
    const float* Wih_f = (const float*)d_in[2];
    const float* Whh_f = (const float*)d_in[3];
    const float* bih_f = (const float*)d_in[4];
    const float* bhh_f = (const float*)d_in[5];
    const float* Wih_b = (const float*)d_in[6];
    const float* Whh_b = (const float*)d_in[7];
    const float* bih_b = (const float*)d_in[8];
    const float* bhh_b = (const float*)d_in[9];
    const float* W_mu  = (const float*)d_in[10];
    const float* b_mu  = (const float*)d_in[11];
    const float* W_sig = (const float*)d_in[12];
    const float* b_sig = (const float*)d_in[13];
    const float* eps   = (const float*)d_in[14];
    float* out = (float*)d_out;

    char* ws = (char*)d_ws;
    __bf16* Xbf  = (__bf16*)(ws);                   // 41943040
    __bf16* Wk1  = (__bf16*)(ws + 41943040);        //  1966080
    __bf16* Wk2  = (__bf16*)(ws + 43909120);        //  3145728
    __bf16* Hb0  = (__bf16*)(ws + 47054848);        //  2097152
    __bf16* Hb1  = (__bf16*)(ws + 49152000);        //  2097152
    float*  Ssum = (float*) (ws + 51249152);        //  4194304
    __bf16* Avg  = (__bf16*)(ws + 55443456);        //  1048576
    __bf16* Wcat = (__bf16*)(ws + 56492032);        //   262144
    unsigned* cntp = (unsigned*)(ws + 56754176);    //     8192 (32 chains x 256 B)
    // total 56762368 bytes

    prep_text<<<8192, 320, 0, stream>>>(text, Xbf);
    prep_w<<<10496, 256, 0, stream>>>(Wih_f, Whh_f, Wih_b, Whh_b, W_mu, W_sig,
                                      Wk1, Wk2, Wcat, cntp);

    void* args[] = { (void*)&Xbf, (void*)&Wk1, (void*)&Wk2,
                     (void*)&bih_f, (void*)&bhh_f, (void*)&bih_b, (void*)&bhh_b,
                     (void*)&lens, (void*)&Hb0, (void*)&Hb1,
                     (void*)&Ssum, (void*)&cntp };
    hipError_t ce = hipLaunchCooperativeKernel((void*)gru_persist, dim3(256),
                                               dim3(512), args, 0, stream);
    if (ce != hipSuccess) {
        // 256 blocks x 512 thr = 1 block/CU: co-resident even under plain launch
        gru_persist<<<256, 512, 0, stream>>>(Xbf, Wk1, Wk2,
                                             bih_f, bhh_f, bih_b, bhh_b,
                                             lens, Hb0, Hb1, Ssum, cntp);
    }

    avg_prep<<<B_, 128, 0, stream>>>(Ssum, lens, Avg);
    head_gemm<<<64, 256, 0, stream>>>(Avg, Wcat, b_mu, b_sig, out);
    final_k<<<512, 256, 0, stream>>>(eps, out);
}